// Round 5
// baseline (174.419 us; speedup 1.0000x reference)
//
#include <hip/hip_runtime.h>

// Ordered bi-bi mechanism dydt. Species: [E, EA, EQ, EAB, A, B, P, Q].
// Lane pair (2j, 2j+1) holds the two float4 halves of element j -> every
// global access is unit-stride float4 across the wave. Halves + rates
// exchanged via __shfl_xor(.,1).
// Round-4 finding: access-pattern changes don't move dur (55-58 us fixed);
// no pipe saturated -> latency/concurrency-bound. This version gives each
// thread 8 rows with all 16 loads issued before first use (4x outstanding
// bytes per wave, 4x fewer wave launches).

typedef float nfloat4 __attribute__((ext_vector_type(4)));

constexpr int RPT = 8;  // rows (float4 of y) per thread

__device__ __forceinline__ nfloat4 process_row(float4 q, float4 mine, int h) {
    // q = this lane's y half; mine = kf row (even lane) / kr row (odd lane)
    float4 p;
    p.x = __shfl_xor(q.x, 1);
    p.y = __shfl_xor(q.y, 1);
    p.z = __shfl_xor(q.z, 1);
    p.w = __shfl_xor(q.w, 1);

    float4 ya = h ? p : q;   // E, EA, EQ, EAB
    float4 yb = h ? q : p;   // A, B, P, Q

    float4 other;
    other.x = __shfl_xor(mine.x, 1);
    other.y = __shfl_xor(mine.y, 1);
    other.z = __shfl_xor(mine.z, 1);
    other.w = __shfl_xor(mine.w, 1);

    float4 f = h ? other : mine;   // kf0..kf3
    float4 r = h ? mine : other;   // kr0..kr3

    float E  = ya.x, EA = ya.y, EQ = ya.z, EAB = ya.w;
    float A  = yb.x, Bc = yb.y, P  = yb.z, Q   = yb.w;

    float v0 = f.x * E   * A  - r.x * EA;
    float v1 = f.y * EA  * Bc - r.y * EAB;
    float v2 = f.z * EAB      - r.z * EQ * P;
    float v3 = f.w * EQ       - r.w * E  * Q;

    nfloat4 o;
    if (h == 0) {
        o.x = v3 - v0;   // dE
        o.y = v0 - v1;   // dEA
        o.z = v2 - v3;   // dEQ
        o.w = v1 - v2;   // dEAB
    } else {
        o.x = -v0;       // dA
        o.y = -v1;       // dB
        o.z =  v2;       // dP
        o.w =  v3;       // dQ
    }
    return o;
}

__global__ __launch_bounds__(256) void ode_kernel(
    const float4* __restrict__ y4,
    const float4* __restrict__ kf4,
    const float4* __restrict__ kr4,
    nfloat4* __restrict__ out4,
    int n2)   // n2 = 2*B float4 rows
{
    const int tid = threadIdx.x;
    const int h   = tid & 1;  // stride-256 rows keep parity constant per thread
    const int base = blockIdx.x * (256 * RPT) + tid;

    if (base + 256 * (RPT - 1) < n2) {
        // full block: issue all 16 loads before any use
        float4 q[RPT], m[RPT];
        #pragma unroll
        for (int k = 0; k < RPT; ++k) {
            int r = base + k * 256;
            q[k] = y4[r];
            m[k] = (h ? kr4 : kf4)[r >> 1];
        }
        #pragma unroll
        for (int k = 0; k < RPT; ++k) {
            nfloat4 o = process_row(q[k], m[k], h);
            __builtin_nontemporal_store(o, &out4[base + k * 256]);
        }
    } else {
        // tail block: per-row guard
        #pragma unroll
        for (int k = 0; k < RPT; ++k) {
            int r = base + k * 256;
            if (r < n2) {
                float4 qq = y4[r];
                float4 mm = (h ? kr4 : kf4)[r >> 1];
                nfloat4 o = process_row(qq, mm, h);
                __builtin_nontemporal_store(o, &out4[r]);
            }
        }
    }
}

extern "C" void kernel_launch(void* const* d_in, const int* in_sizes, int n_in,
                              void* d_out, int out_size, void* d_ws, size_t ws_size,
                              hipStream_t stream) {
    // inputs: [0]=t (1,), [1]=y (B,8), [2]=forward_rates (B,4), [3]=reverse_rates (B,4)
    const float4* y4  = (const float4*)d_in[1];
    const float4* kf4 = (const float4*)d_in[2];
    const float4* kr4 = (const float4*)d_in[3];
    nfloat4* out4 = (nfloat4*)d_out;
    int B  = in_sizes[1] / 8;
    int n2 = 2 * B;

    int block = 256;
    int rows_per_block = block * RPT;
    int grid = (n2 + rows_per_block - 1) / rows_per_block;
    ode_kernel<<<grid, block, 0, stream>>>(y4, kf4, kr4, out4, n2);
}

// Round 6
// 173.372 us; speedup vs baseline: 1.0060x; 1.0060x over previous
//
#include <hip/hip_runtime.h>

// Ordered bi-bi mechanism dydt. Species: [E, EA, EQ, EAB, A, B, P, Q].
// Lane pair (2j, 2j+1) holds the two float4 halves of element j -> every
// global access is unit-stride float4 across the wave; halves + rates are
// exchanged via __shfl_xor(.,1).
//
// Round 2-5 finding: one-shot-wave variants are all pinned at 55-62 us
// (3.4 TB/s effective) with no pipe saturated and dur invariant to HBM
// traffic -> concurrency/wave-churn limit, not bandwidth. This version uses
// PERSISTENT waves at max occupancy (2048 blocks x 256 thr = 32 waves/CU)
// with a grid-stride loop and register double-buffering: next iteration's
// two loads are issued before current iteration's compute+store, keeping the
// vmem queue non-empty for the wave's whole life.

typedef float nfloat4 __attribute__((ext_vector_type(4)));

__device__ __forceinline__ nfloat4 process_row(float4 q, float4 mine, int h) {
    // q = this lane's y half; mine = kf row (even lane) / kr row (odd lane)
    float4 p;
    p.x = __shfl_xor(q.x, 1);
    p.y = __shfl_xor(q.y, 1);
    p.z = __shfl_xor(q.z, 1);
    p.w = __shfl_xor(q.w, 1);

    float4 ya = h ? p : q;   // E, EA, EQ, EAB
    float4 yb = h ? q : p;   // A, B, P, Q

    float4 other;
    other.x = __shfl_xor(mine.x, 1);
    other.y = __shfl_xor(mine.y, 1);
    other.z = __shfl_xor(mine.z, 1);
    other.w = __shfl_xor(mine.w, 1);

    float4 f = h ? other : mine;   // kf0..kf3
    float4 r = h ? mine : other;   // kr0..kr3

    float E  = ya.x, EA = ya.y, EQ = ya.z, EAB = ya.w;
    float A  = yb.x, Bc = yb.y, P  = yb.z, Q   = yb.w;

    float v0 = f.x * E   * A  - r.x * EA;
    float v1 = f.y * EA  * Bc - r.y * EAB;
    float v2 = f.z * EAB      - r.z * EQ * P;
    float v3 = f.w * EQ       - r.w * E  * Q;

    nfloat4 o;
    if (h == 0) {
        o.x = v3 - v0;   // dE
        o.y = v0 - v1;   // dEA
        o.z = v2 - v3;   // dEQ
        o.w = v1 - v2;   // dEAB
    } else {
        o.x = -v0;       // dA
        o.y = -v1;       // dB
        o.z =  v2;       // dP
        o.w =  v3;       // dQ
    }
    return o;
}

__global__ __launch_bounds__(256) void ode_kernel(
    const float4* __restrict__ y4,
    const float4* __restrict__ kf4,
    const float4* __restrict__ kr4,
    nfloat4* __restrict__ out4,
    int n2)   // n2 = 2*B float4 rows
{
    const int t = blockIdx.x * 256 + threadIdx.x;
    const int S = gridDim.x * 256;     // even -> parity of r is constant
    const int h = t & 1;
    const float4* __restrict__ rp = h ? kr4 : kf4;

    int r = t;
    if (r >= n2) return;

    // prime the pipeline
    float4 q = y4[r];
    float4 m = rp[r >> 1];

    for (int rn = r + S; rn < n2; rn += S) {
        // issue next iteration's loads BEFORE consuming current's
        float4 qn = y4[rn];
        float4 mn = rp[rn >> 1];

        nfloat4 o = process_row(q, m, h);
        __builtin_nontemporal_store(o, &out4[r]);

        q = qn; m = mn; r = rn;
    }

    nfloat4 o = process_row(q, m, h);
    __builtin_nontemporal_store(o, &out4[r]);
}

extern "C" void kernel_launch(void* const* d_in, const int* in_sizes, int n_in,
                              void* d_out, int out_size, void* d_ws, size_t ws_size,
                              hipStream_t stream) {
    // inputs: [0]=t (1,), [1]=y (B,8), [2]=forward_rates (B,4), [3]=reverse_rates (B,4)
    const float4* y4  = (const float4*)d_in[1];
    const float4* kf4 = (const float4*)d_in[2];
    const float4* kr4 = (const float4*)d_in[3];
    nfloat4* out4 = (nfloat4*)d_out;
    int B  = in_sizes[1] / 8;
    int n2 = 2 * B;

    // persistent grid: 2048 blocks x 256 = 524288 threads = 32 waves/CU on 256 CUs
    int block = 256;
    int full  = (n2 + block - 1) / block;
    int grid  = full < 2048 ? full : 2048;
    ode_kernel<<<grid, block, 0, stream>>>(y4, kf4, kr4, out4, n2);
}